// Round 15
// baseline (1961.578 us; speedup 1.0000x reference)
//
#include <hip/hip_runtime.h>

#define NJ 32
#define NE 1024
#define CD 128
#define HID 256
#define ROWS 8192

struct Lv { int nj; int j[5]; int p[5]; };

typedef __attribute__((ext_vector_type(2))) float f2;
typedef __attribute__((ext_vector_type(16))) float f16v;

// packed fp32 FMA: acc.{lo,hi} += s0.lo * s1.{lo,hi}   (broadcast lo of s0)
#define PKLO(acc, s0, s1) \
  asm("v_pk_fma_f32 %0, %1, %2, %0 op_sel:[0,0,0] op_sel_hi:[0,1,1]" \
      : "+v"(acc) : "v"(s0), "v"(s1))
// packed fp32 FMA: acc.{lo,hi} += s0.hi * s1.{lo,hi}   (broadcast hi of s0)
#define PKHI(acc, s0, s1) \
  asm("v_pk_fma_f32 %0, %1, %2, %0 op_sel:[1,0,0] op_sel_hi:[1,1,1]" \
      : "+v"(acc) : "v"(s0), "v"(s1))

// ---------------------------------------------------------------------------
// codebook norms: nrm[j*NE+n] = sum_c emb[j][n][c]^2   (4 lanes per code row)
// ---------------------------------------------------------------------------
__global__ __launch_bounds__(256) void norms_kernel(const float* __restrict__ emb,
                                                    float* __restrict__ nrm) {
  int gid = blockIdx.x * 256 + threadIdx.x;
  int n = gid >> 2, l = gid & 3;           // n in [0, NJ*NE)
  const float* row = emb + (size_t)n * CD;
  float s = 0.f;
#pragma unroll
  for (int i = 0; i < 8; ++i) {
    float4 v = *(const float4*)&row[(l + 4 * i) * 4];
    s += v.x * v.x + v.y * v.y + v.z * v.z + v.w * v.w;
  }
  s += __shfl_xor(s, 1);
  s += __shfl_xor(s, 2);
  if (l == 0) nrm[n] = s;
}

// ---------------------------------------------------------------------------
// fused per-level kernel — round-14 structure; when HT=1 (big levels, ws
// permitting), phase 4's wave-uniform h reads come from a transposed copy in
// global scratch (uniform 64B loads -> scalar/L1 path) instead of the LDS
// port, cutting phase-4 LDS ops from 6 to 2 b128 per kk. Bit-identical FP.
// ---------------------------------------------------------------------------
template <int RB, int HT>
__global__ __launch_bounds__(256) void fused_level(
    const float* __restrict__ z, const float* __restrict__ emb,
    const float* __restrict__ W1, const float* __restrict__ b1,
    const float* __restrict__ lng, const float* __restrict__ lnb,
    const float* __restrict__ W2, const float* __restrict__ b2,
    const float* __restrict__ nrm, float* __restrict__ hT,
    float* __restrict__ zq, float* __restrict__ idx_out,
    float* __restrict__ partials, Lv lv, int pbase) {
  constexpr int RPG = RB / 8;          // rows/thread, phases 1-3
  constexpr int R4 = RB / 4;           // rows/thread, phase 4
  constexpr int HSP = RB + 4;
  constexpr int BPJ = ROWS / RB;
  constexpr int XS_SZ = 32 * HSP;
  constexpr int HS_SZ = 128 * HSP;
  constexpr int P1 = XS_SZ + 8448;
  constexpr int P3 = HS_SZ + 2112;
  constexpr int P4 = HS_SZ + 16 * 516 + 512;
  constexpr int SM12 = (P1 > P3) ? P1 : P3;
  constexpr int SMEM = (SM12 > P4) ? SM12 : P4;

  __shared__ __align__(16) float smem[SMEM];
  __shared__ float wsum[4];
  float* xs  = smem;
  float* ws1 = smem + XS_SZ;
  float* as_ = smem;
  float* ws2 = smem + HS_SZ;
  float* hs  = smem;
  float* es  = smem + HS_SZ;
  float* nsm = smem + HS_SZ + 16 * 516;

  const int tid = threadIdx.x;
  const int rg = tid >> 5, cg = tid & 31;
  const int u = cg & 15;
  const int qcA = (cg >> 4) * 128 + u * 4;
  const int qcB = qcA + 64;
  const int jl = blockIdx.x / BPJ;
  const int row0 = (blockIdx.x % BPJ) * RB;
  const int jj = lv.j[jl], pj = lv.p[jl];
  const size_t rstride = (size_t)NJ * CD;
  float* hTblk = HT ? (hT + (size_t)(jl * BPJ + (blockIdx.x % BPJ)) * (64 * 128))
                    : nullptr;

  if (pj >= 0) {
    // ================= phase 1: a1 = [e_parent | z_j] @ W1 =================
    f2 acc1[RPG][4];
#pragma unroll
    for (int r = 0; r < RPG; ++r)
#pragma unroll
      for (int c = 0; c < 4; ++c) acc1[r][c] = (f2){0.f, 0.f};

#pragma unroll 1
    for (int ks = 0; ks < 8; ++ks) {
#pragma unroll
      for (int uu = 0; uu < RB / 32; ++uu) {
        int idx = uu * 256 + tid;
        int r = idx >> 3, kq = idx & 7;
        const float* src = (ks < 4)
            ? (zq + (size_t)(row0 + r) * rstride + (size_t)pj * CD + (ks * 32 + kq * 4))
            : (z  + (size_t)(row0 + r) * rstride + (size_t)jj * CD + (ks * 32 - 128 + kq * 4));
        float4 v = *(const float4*)src;
        xs[(kq * 4 + 0) * HSP + r] = v.x;
        xs[(kq * 4 + 1) * HSP + r] = v.y;
        xs[(kq * 4 + 2) * HSP + r] = v.z;
        xs[(kq * 4 + 3) * HSP + r] = v.w;
      }
#pragma unroll
      for (int v8 = 0; v8 < 8; ++v8) {
        int idx = v8 * 256 + tid;
        int k = idx >> 6, c4 = idx & 63;
        *(float4*)&ws1[k * 264 + c4 * 4] =
            *(const float4*)&W1[(size_t)(ks * 32 + k) * HID + c4 * 4];
      }
      __syncthreads();
#pragma unroll 2
      for (int kk = 0; kk < 32; ++kk) {
        f2 xrp[RPG / 2], wcp[4];
#pragma unroll
        for (int g = 0; g < RPG / 4; ++g)
          *(float4*)&xrp[g * 2] = *(const float4*)&xs[kk * HSP + rg * RPG + g * 4];
        *(float4*)&wcp[0] = *(const float4*)&ws1[kk * 264 + qcA];
        *(float4*)&wcp[2] = *(const float4*)&ws1[kk * 264 + qcB];
#pragma unroll
        for (int r2 = 0; r2 < RPG / 2; ++r2) {
#pragma unroll
          for (int c = 0; c < 4; ++c) PKLO(acc1[2 * r2][c], xrp[r2], wcp[c]);
#pragma unroll
          for (int c = 0; c < 4; ++c) PKHI(acc1[2 * r2 + 1][c], xrp[r2], wcp[c]);
        }
      }
      __syncthreads();
    }

    // ====== phase 2: +b1, LayerNorm, ReLU — round-1 bit-exact tree =========
    {
      float bb[8], gg[8], be[8];
      *(float4*)&bb[0] = *(const float4*)&b1[qcA];
      *(float4*)&bb[4] = *(const float4*)&b1[qcB];
      *(float4*)&gg[0] = *(const float4*)&lng[qcA];
      *(float4*)&gg[4] = *(const float4*)&lng[qcB];
      *(float4*)&be[0] = *(const float4*)&lnb[qcA];
      *(float4*)&be[4] = *(const float4*)&lnb[qcB];
#pragma unroll
      for (int r = 0; r < RPG; ++r) {
        float s0 = 0.f, q0 = 0.f;
#pragma unroll
        for (int j = 0; j < 8; ++j) {
          float v = acc1[r][j >> 1][j & 1] + bb[j];
          acc1[r][j >> 1][j & 1] = v;
          s0 += v; q0 += v * v;
        }
        float si = __shfl_xor(s0, 16), qi = __shfl_xor(q0, 16);
        float s1 = si, q1 = qi;
#pragma unroll
        for (int j = 0; j < 8; ++j) {
          float v = acc1[r][j >> 1][j & 1];
          s1 += v; q1 += v * v;
        }
#pragma unroll
        for (int m = 1; m < 16; m <<= 1) {
          s1 += __shfl_xor(s1, m); q1 += __shfl_xor(q1, m);
        }
        float s2 = __shfl_xor(s1, 16), q2 = __shfl_xor(q1, 16);
        float Sx = (cg & 16) ? s1 : s2;
        float Qx = (cg & 16) ? q1 : q2;
        float mu = Sx * (1.f / HID);
        float va = Qx * (1.f / HID) - mu * mu;
        float iv = 1.f / sqrtf(va + 1e-5f);
#pragma unroll
        for (int j = 0; j < 8; ++j) {
          float a = (acc1[r][j >> 1][j & 1] - mu) * iv * gg[j] + be[j];
          acc1[r][j >> 1][j & 1] = fmaxf(a, 0.f);
        }
      }
    }

    // ================= phase 3: h = a @ W2 + b2 (two 128-k halves) =========
    f2 acc2[RPG][2];
#pragma unroll
    for (int r = 0; r < RPG; ++r)
#pragma unroll
      for (int c = 0; c < 2; ++c) acc2[r][c] = (f2){0.f, 0.f};

#pragma unroll 1
    for (int half = 0; half < 2; ++half) {
      __syncthreads();
      if ((cg >> 4) == half) {
#pragma unroll
        for (int j = 0; j < 8; ++j) {
          int kl = (j >> 2) * 64 + u * 4 + (j & 3);
#pragma unroll
          for (int g = 0; g < RPG; ++g)
            as_[kl * HSP + rg * RPG + g] = acc1[g][j >> 1][j & 1];
        }
      }
      __syncthreads();
#pragma unroll 1
      for (int kc = 0; kc < 8; ++kc) {
#pragma unroll
        for (int v = 0; v < 2; ++v) {
          int idx = v * 256 + tid;
          int k = idx >> 5, c4 = idx & 31;
          *(float4*)&ws2[k * 132 + c4 * 4] =
              *(const float4*)&W2[(size_t)(half * 128 + kc * 16 + k) * CD + c4 * 4];
        }
        __syncthreads();
#pragma unroll 2
        for (int kk = 0; kk < 16; ++kk) {
          f2 arp[RPG / 2], w2p[2];
#pragma unroll
          for (int g = 0; g < RPG / 4; ++g)
            *(float4*)&arp[g * 2] =
                *(const float4*)&as_[(kc * 16 + kk) * HSP + rg * RPG + g * 4];
          *(float4*)&w2p[0] = *(const float4*)&ws2[kk * 132 + cg * 4];
#pragma unroll
          for (int r2 = 0; r2 < RPG / 2; ++r2) {
#pragma unroll
            for (int c = 0; c < 2; ++c) PKLO(acc2[2 * r2][c], arp[r2], w2p[c]);
#pragma unroll
            for (int c = 0; c < 2; ++c) PKHI(acc2[2 * r2 + 1][c], arp[r2], w2p[c]);
          }
        }
        __syncthreads();
      }
    }
    {
      float4 bv = *(const float4*)&b2[cg * 4];
      float bb2[4] = {bv.x, bv.y, bv.z, bv.w};
#pragma unroll
      for (int c = 0; c < 4; ++c) {
#pragma unroll
        for (int g = 0; g < RPG / 4; ++g) {
          float4 hv4 = make_float4(acc2[g * 4 + 0][c >> 1][c & 1] + bb2[c],
                                   acc2[g * 4 + 1][c >> 1][c & 1] + bb2[c],
                                   acc2[g * 4 + 2][c >> 1][c & 1] + bb2[c],
                                   acc2[g * 4 + 3][c >> 1][c & 1] + bb2[c]);
          *(float4*)&hs[(cg * 4 + c) * HSP + rg * RPG + g * 4] = hv4;
          if constexpr (HT)
            *(float4*)&hTblk[(cg * 4 + c) * 64 + rg * RPG + g * 4] = hv4;
        }
      }
    }
  } else {
    // root joint: h = z_j directly
#pragma unroll
    for (int v = 0; v < RB / 8; ++v) {
      int idx = v * 256 + tid;
      int r = idx >> 5, c4 = idx & 31;
      float4 vz = *(const float4*)&z[(size_t)(row0 + r) * rstride + (size_t)jj * CD + c4 * 4];
      hs[(c4 * 4 + 0) * HSP + r] = vz.x;
      hs[(c4 * 4 + 1) * HSP + r] = vz.y;
      hs[(c4 * 4 + 2) * HSP + r] = vz.z;
      hs[(c4 * 4 + 3) * HSP + r] = vz.w;
      if constexpr (HT) {
        hTblk[(c4 * 4 + 0) * 64 + r] = vz.x;
        hTblk[(c4 * 4 + 1) * 64 + r] = vz.y;
        hTblk[(c4 * 4 + 2) * 64 + r] = vz.z;
        hTblk[(c4 * 4 + 3) * 64 + r] = vz.w;
      }
    }
  }

  // ====== phase 4: d = ||E||^2 - 2 h.E ; R4 rows x 8 codes per thread ======
  const int w4 = tid >> 6;     // wave owns rows w4*R4 .. +R4-1
  const int l4 = tid & 63;     // lane owns codes {l4*4..+3} and {256+l4*4..+3}
  float mnv[R4]; int mni[R4];
#pragma unroll
  for (int r = 0; r < R4; ++r) { mnv[r] = 3.402823e38f; mni[r] = 0; }
  const float* embJ = emb + (size_t)jj * NE * CD;
  const float* nrmJ = nrm + jj * NE;

  if constexpr (HT) {
    // h rows via wave-uniform 64B global loads (scalar/L1 path, off LDS port)
    const int w4u = __builtin_amdgcn_readfirstlane(w4);
    const float* hTw = hTblk + w4u * 16;
#pragma unroll 1
    for (int p = 0; p < 2; ++p) {
      __syncthreads();
      if (tid < 128) {
        *(float4*)&nsm[tid * 4] = *(const float4*)&nrmJ[p * 512 + tid * 4];
      }
      float acc4[R4][8];
#pragma unroll
      for (int r = 0; r < R4; ++r)
#pragma unroll
        for (int c = 0; c < 8; ++c) acc4[r][c] = 0.f;

#pragma unroll 1
      for (int kc = 0; kc < 8; ++kc) {
#pragma unroll
        for (int v = 0; v < 8; ++v) {
          int idx = v * 256 + tid;
          int n = idx >> 2, kq = idx & 3;
          float4 ev = *(const float4*)&embJ[(size_t)(p * 512 + n) * CD + kc * 16 + kq * 4];
          es[(kq * 4 + 0) * 516 + n] = ev.x;
          es[(kq * 4 + 1) * 516 + n] = ev.y;
          es[(kq * 4 + 2) * 516 + n] = ev.z;
          es[(kq * 4 + 3) * 516 + n] = ev.w;
        }
        __syncthreads();
#pragma unroll 2
        for (int kk = 0; kk < 16; ++kk) {
          int c = kc * 16 + kk;
          f16v hv = *(const f16v*)(hTw + c * 64);
          float ec[8];
          *(float4*)&ec[0] = *(const float4*)&es[kk * 516 + l4 * 4];
          *(float4*)&ec[4] = *(const float4*)&es[kk * 516 + 256 + l4 * 4];
#pragma unroll
          for (int r = 0; r < R4; ++r)
#pragma unroll
            for (int c2 = 0; c2 < 8; ++c2)
              acc4[r][c2] += hv[r] * ec[c2];
        }
        __syncthreads();
      }
#pragma unroll
      for (int r = 0; r < R4; ++r) {
#pragma unroll
        for (int q = 0; q < 2; ++q) {
#pragma unroll
          for (int j = 0; j < 4; ++j) {
            int nl = q * 256 + l4 * 4 + j;
            float d = nsm[nl] - 2.f * acc4[r][q * 4 + j];
            int n = p * 512 + nl;
            if (d < mnv[r]) { mnv[r] = d; mni[r] = n; }
          }
        }
      }
    }
  } else {
#pragma unroll 1
    for (int p = 0; p < 2; ++p) {
      __syncthreads();
      if (tid < 128) {
        *(float4*)&nsm[tid * 4] = *(const float4*)&nrmJ[p * 512 + tid * 4];
      }
      f2 acc4[R4][4];
#pragma unroll
      for (int r = 0; r < R4; ++r)
#pragma unroll
        for (int c = 0; c < 4; ++c) acc4[r][c] = (f2){0.f, 0.f};

#pragma unroll 1
      for (int kc = 0; kc < 8; ++kc) {
#pragma unroll
        for (int v = 0; v < 8; ++v) {
          int idx = v * 256 + tid;
          int n = idx >> 2, kq = idx & 3;
          float4 ev = *(const float4*)&embJ[(size_t)(p * 512 + n) * CD + kc * 16 + kq * 4];
          es[(kq * 4 + 0) * 516 + n] = ev.x;
          es[(kq * 4 + 1) * 516 + n] = ev.y;
          es[(kq * 4 + 2) * 516 + n] = ev.z;
          es[(kq * 4 + 3) * 516 + n] = ev.w;
        }
        __syncthreads();
#pragma unroll 2
        for (int kk = 0; kk < 16; ++kk) {
          int c = kc * 16 + kk;
          f2 hrp[R4 / 2], ecp[4];
#pragma unroll
          for (int g = 0; g < R4 / 4; ++g)
            *(float4*)&hrp[g * 2] = *(const float4*)&hs[c * HSP + w4 * R4 + g * 4];
          *(float4*)&ecp[0] = *(const float4*)&es[kk * 516 + l4 * 4];
          *(float4*)&ecp[2] = *(const float4*)&es[kk * 516 + 256 + l4 * 4];
#pragma unroll
          for (int r2 = 0; r2 < R4 / 2; ++r2) {
#pragma unroll
            for (int c2 = 0; c2 < 4; ++c2) PKLO(acc4[2 * r2][c2], hrp[r2], ecp[c2]);
#pragma unroll
            for (int c2 = 0; c2 < 4; ++c2) PKHI(acc4[2 * r2 + 1][c2], hrp[r2], ecp[c2]);
          }
        }
        __syncthreads();
      }
#pragma unroll
      for (int r = 0; r < R4; ++r) {
#pragma unroll
        for (int q = 0; q < 2; ++q) {
#pragma unroll
          for (int j = 0; j < 4; ++j) {
            int nl = q * 256 + l4 * 4 + j;
            int ci = q * 4 + j;
            float d = nsm[nl] - 2.f * acc4[r][ci >> 1][ci & 1];
            int n = p * 512 + nl;
            if (d < mnv[r]) { mnv[r] = d; mni[r] = n; }
          }
        }
      }
    }
  }

  // cross-lane argmin reduce over 64 lanes, tie -> smaller index
#pragma unroll
  for (int r = 0; r < R4; ++r) {
    float mv = mnv[r]; int mi = mni[r];
#pragma unroll
    for (int m = 1; m < 64; m <<= 1) {
      float om = __shfl_xor(mv, m); int oi = __shfl_xor(mi, m);
      if (om < mv || (om == mv && oi < mi)) { mv = om; mi = oi; }
    }
    mnv[r] = mv; mni[r] = mi;
  }

  // gather e, write z_q + indices, accumulate loss (lane covers 2 cols)
  float lsum = 0.f;
#pragma unroll
  for (int r = 0; r < R4; ++r) {
    int row = w4 * R4 + r;
    int id = mni[r];
    const float* erow = embJ + (size_t)id * CD;
    float2 ev = *(const float2*)&erow[l4 * 2];
    float h0 = hs[(l4 * 2 + 0) * HSP + row];
    float h1 = hs[(l4 * 2 + 1) * HSP + row];
    float dx = ev.x - h0, dy = ev.y - h1;
    lsum += dx * dx + dy * dy;
    *(float2*)&zq[(size_t)(row0 + row) * rstride + (size_t)jj * CD + l4 * 2] = ev;
    if (l4 == r) idx_out[(size_t)(row0 + row) * NJ + jj] = (float)id;
  }
#pragma unroll
  for (int m = 1; m < 64; m <<= 1) lsum += __shfl_xor(lsum, m);
  if (l4 == 0) wsum[w4] = lsum;
  __syncthreads();
  if (tid == 0) partials[pbase + blockIdx.x] = wsum[0] + wsum[1] + wsum[2] + wsum[3];
}

// ---------------------------------------------------------------------------
// deterministic loss reduction
// ---------------------------------------------------------------------------
__global__ __launch_bounds__(256) void loss_reduce(const float* __restrict__ p, int n,
                                                   float* __restrict__ out) {
  __shared__ float ws[4];
  float s = 0.f;
  for (int i = threadIdx.x; i < n; i += 256) s += p[i];
#pragma unroll
  for (int m = 1; m < 64; m <<= 1) s += __shfl_xor(s, m);
  if ((threadIdx.x & 63) == 0) ws[threadIdx.x >> 6] = s;
  __syncthreads();
  if (threadIdx.x == 0)
    out[0] = (ws[0] + ws[1] + ws[2] + ws[3]) * (1.25f / (1048576.f * 32.f));
}

extern "C" void kernel_launch(void* const* d_in, const int* in_sizes, int n_in,
                              void* d_out, int out_size, void* d_ws, size_t ws_size,
                              hipStream_t stream) {
  const float* z = (const float*)d_in[0];
  const float* emb = (const float*)d_in[1];
  const float* W1 = (const float*)d_in[2];
  const float* b1 = (const float*)d_in[3];
  const float* lng = (const float*)d_in[4];
  const float* lnb = (const float*)d_in[5];
  const float* W2 = (const float*)d_in[6];
  const float* b2 = (const float*)d_in[7];

  float* zq = (float*)d_out;
  float* loss = zq + (size_t)ROWS * NJ * CD;  // 33,554,432
  float* idxo = loss + 1;

  float* nrm = (float*)d_ws;                       // NJ*NE floats
  float* partials = nrm + NJ * NE;                 // <= 5760 floats
  float* hT = (float*)((char*)d_ws + 163840);      // 640 slots x 32KB

  const size_t NEEDED = 163840 + (size_t)640 * 64 * 128 * 4;
  const bool use_ht = (ws_size >= NEEDED);

  norms_kernel<<<NJ * NE * 4 / 256, 256, 0, stream>>>(emb, nrm);

  static const Lv levels[11] = {
      {1, {0, 0, 0, 0, 0}, {-1, 0, 0, 0, 0}},
      {3, {1, 6, 11, 0, 0}, {0, 0, 0, 0, 0}},
      {3, {2, 7, 12, 0, 0}, {1, 6, 11, 0, 0}},
      {5, {3, 8, 13, 16, 24}, {2, 7, 12, 12, 12}},
      {5, {4, 9, 14, 17, 25}, {3, 8, 13, 16, 24}},
      {5, {5, 10, 15, 18, 26}, {4, 9, 14, 17, 25}},
      {2, {19, 27, 0, 0, 0}, {18, 26, 0, 0, 0}},
      {2, {20, 28, 0, 0, 0}, {19, 27, 0, 0, 0}},
      {2, {21, 29, 0, 0, 0}, {20, 28, 0, 0, 0}},
      {2, {22, 30, 0, 0, 0}, {21, 29, 0, 0, 0}},
      {2, {23, 31, 0, 0, 0}, {22, 30, 0, 0, 0}},
  };
  // RB per level: root (phase-4-only) 16; nj<=2 levels 32; big levels 64
  static const int rbs[11] = {16, 64, 64, 64, 64, 64, 32, 32, 32, 32, 32};

  int pbase = 0;
  for (int L = 0; L < 11; ++L) {
    int bpj = ROWS / rbs[L];
    int blocks = levels[L].nj * bpj;
    if (rbs[L] == 64) {
      if (use_ht) {
        fused_level<64, 1><<<blocks, 256, 0, stream>>>(
            z, emb, W1, b1, lng, lnb, W2, b2, nrm, hT, zq, idxo, partials,
            levels[L], pbase);
      } else {
        fused_level<64, 0><<<blocks, 256, 0, stream>>>(
            z, emb, W1, b1, lng, lnb, W2, b2, nrm, hT, zq, idxo, partials,
            levels[L], pbase);
      }
    } else if (rbs[L] == 32) {
      fused_level<32, 0><<<blocks, 256, 0, stream>>>(
          z, emb, W1, b1, lng, lnb, W2, b2, nrm, hT, zq, idxo, partials,
          levels[L], pbase);
    } else {
      fused_level<16, 0><<<blocks, 256, 0, stream>>>(
          z, emb, W1, b1, lng, lnb, W2, b2, nrm, hT, zq, idxo, partials,
          levels[L], pbase);
    }
    pbase += blocks;
  }
  loss_reduce<<<1, 256, 0, stream>>>(partials, pbase, loss);
}

// Round 16
// 1834.697 us; speedup vs baseline: 1.0692x; 1.0692x over previous
//
#include <hip/hip_runtime.h>

#define NJ 32
#define NE 1024
#define CD 128
#define HID 256
#define ROWS 8192

struct Lv { int nj; int j[5]; int p[5]; };

typedef __attribute__((ext_vector_type(2))) float f2;

// packed fp32 FMA: acc.{lo,hi} += s0.lo * s1.{lo,hi}   (broadcast lo of s0)
#define PKLO(acc, s0, s1) \
  asm("v_pk_fma_f32 %0, %1, %2, %0 op_sel:[0,0,0] op_sel_hi:[0,1,1]" \
      : "+v"(acc) : "v"(s0), "v"(s1))
// packed fp32 FMA: acc.{lo,hi} += s0.hi * s1.{lo,hi}   (broadcast hi of s0)
#define PKHI(acc, s0, s1) \
  asm("v_pk_fma_f32 %0, %1, %2, %0 op_sel:[1,0,0] op_sel_hi:[1,1,1]" \
      : "+v"(acc) : "v"(s0), "v"(s1))

// ---------------------------------------------------------------------------
// codebook norms: nrm[j*NE+n] = sum_c emb[j][n][c]^2   (4 lanes per code row)
// ---------------------------------------------------------------------------
__global__ __launch_bounds__(256) void norms_kernel(const float* __restrict__ emb,
                                                    float* __restrict__ nrm) {
  int gid = blockIdx.x * 256 + threadIdx.x;
  int n = gid >> 2, l = gid & 3;           // n in [0, NJ*NE)
  const float* row = emb + (size_t)n * CD;
  float s = 0.f;
#pragma unroll
  for (int i = 0; i < 8; ++i) {
    float4 v = *(const float4*)&row[(l + 4 * i) * 4];
    s += v.x * v.x + v.y * v.y + v.z * v.z + v.w * v.w;
  }
  s += __shfl_xor(s, 1);
  s += __shfl_xor(s, 2);
  if (l == 0) nrm[n] = s;
}

// ---------------------------------------------------------------------------
// fused per-level kernel — round-13 structure with v_pk_fma_f32 inner loops.
// Phases 1-3 (MLP): rg = tid>>5 rows, cg = tid&31 col quads {qcA,qcB}.
// Phase 4 (VQ): wave w4 owns R4 rows; lane l4 owns codes {l4*4, 256+l4*4}
// per 512-code chunk. All per-accumulator FP chains identical to round 13
// (pk halves compute the same IEEE fma per element) -> bit-identical output.
// ---------------------------------------------------------------------------
template <int RB>
__global__ __launch_bounds__(256) void fused_level(
    const float* __restrict__ z, const float* __restrict__ emb,
    const float* __restrict__ W1, const float* __restrict__ b1,
    const float* __restrict__ lng, const float* __restrict__ lnb,
    const float* __restrict__ W2, const float* __restrict__ b2,
    const float* __restrict__ nrm,
    float* __restrict__ zq, float* __restrict__ idx_out,
    float* __restrict__ partials, Lv lv, int pbase) {
  constexpr int RPG = RB / 8;          // rows/thread, phases 1-3
  constexpr int R4 = RB / 4;           // rows/thread, phase 4
  constexpr int HSP = RB + 4;
  constexpr int BPJ = ROWS / RB;
  constexpr int XS_SZ = 32 * HSP;
  constexpr int HS_SZ = 128 * HSP;
  constexpr int P1 = XS_SZ + 8448;
  constexpr int P3 = HS_SZ + 2112;
  constexpr int P4 = HS_SZ + 16 * 516 + 512;
  constexpr int SM12 = (P1 > P3) ? P1 : P3;
  constexpr int SMEM = (SM12 > P4) ? SM12 : P4;

  __shared__ __align__(16) float smem[SMEM];
  __shared__ float wsum[4];
  float* xs  = smem;
  float* ws1 = smem + XS_SZ;
  float* as_ = smem;
  float* ws2 = smem + HS_SZ;
  float* hs  = smem;
  float* es  = smem + HS_SZ;
  float* nsm = smem + HS_SZ + 16 * 516;

  const int tid = threadIdx.x;
  const int rg = tid >> 5, cg = tid & 31;
  const int u = cg & 15;
  const int qcA = (cg >> 4) * 128 + u * 4;
  const int qcB = qcA + 64;
  const int jl = blockIdx.x / BPJ;
  const int row0 = (blockIdx.x % BPJ) * RB;
  const int jj = lv.j[jl], pj = lv.p[jl];
  const size_t rstride = (size_t)NJ * CD;

  if (pj >= 0) {
    // ================= phase 1: a1 = [e_parent | z_j] @ W1 =================
    f2 acc1[RPG][4];
#pragma unroll
    for (int r = 0; r < RPG; ++r)
#pragma unroll
      for (int c = 0; c < 4; ++c) acc1[r][c] = (f2){0.f, 0.f};

#pragma unroll 1
    for (int ks = 0; ks < 8; ++ks) {
#pragma unroll
      for (int uu = 0; uu < RB / 32; ++uu) {
        int idx = uu * 256 + tid;
        int r = idx >> 3, kq = idx & 7;
        const float* src = (ks < 4)
            ? (zq + (size_t)(row0 + r) * rstride + (size_t)pj * CD + (ks * 32 + kq * 4))
            : (z  + (size_t)(row0 + r) * rstride + (size_t)jj * CD + (ks * 32 - 128 + kq * 4));
        float4 v = *(const float4*)src;
        xs[(kq * 4 + 0) * HSP + r] = v.x;
        xs[(kq * 4 + 1) * HSP + r] = v.y;
        xs[(kq * 4 + 2) * HSP + r] = v.z;
        xs[(kq * 4 + 3) * HSP + r] = v.w;
      }
#pragma unroll
      for (int v8 = 0; v8 < 8; ++v8) {
        int idx = v8 * 256 + tid;
        int k = idx >> 6, c4 = idx & 63;
        *(float4*)&ws1[k * 264 + c4 * 4] =
            *(const float4*)&W1[(size_t)(ks * 32 + k) * HID + c4 * 4];
      }
      __syncthreads();
#pragma unroll 2
      for (int kk = 0; kk < 32; ++kk) {
        f2 xrp[RPG / 2], wcp[4];
#pragma unroll
        for (int g = 0; g < RPG / 4; ++g)
          *(float4*)&xrp[g * 2] = *(const float4*)&xs[kk * HSP + rg * RPG + g * 4];
        *(float4*)&wcp[0] = *(const float4*)&ws1[kk * 264 + qcA];
        *(float4*)&wcp[2] = *(const float4*)&ws1[kk * 264 + qcB];
#pragma unroll
        for (int r2 = 0; r2 < RPG / 2; ++r2) {
#pragma unroll
          for (int c = 0; c < 4; ++c) PKLO(acc1[2 * r2][c], xrp[r2], wcp[c]);
#pragma unroll
          for (int c = 0; c < 4; ++c) PKHI(acc1[2 * r2 + 1][c], xrp[r2], wcp[c]);
        }
      }
      __syncthreads();
    }

    // ====== phase 2: +b1, LayerNorm, ReLU — round-1 bit-exact tree =========
    {
      float bb[8], gg[8], be[8];
      *(float4*)&bb[0] = *(const float4*)&b1[qcA];
      *(float4*)&bb[4] = *(const float4*)&b1[qcB];
      *(float4*)&gg[0] = *(const float4*)&lng[qcA];
      *(float4*)&gg[4] = *(const float4*)&lng[qcB];
      *(float4*)&be[0] = *(const float4*)&lnb[qcA];
      *(float4*)&be[4] = *(const float4*)&lnb[qcB];
#pragma unroll
      for (int r = 0; r < RPG; ++r) {
        float s0 = 0.f, q0 = 0.f;
#pragma unroll
        for (int j = 0; j < 8; ++j) {
          float v = acc1[r][j >> 1][j & 1] + bb[j];
          acc1[r][j >> 1][j & 1] = v;
          s0 += v; q0 += v * v;
        }
        float si = __shfl_xor(s0, 16), qi = __shfl_xor(q0, 16);
        float s1 = si, q1 = qi;
#pragma unroll
        for (int j = 0; j < 8; ++j) {
          float v = acc1[r][j >> 1][j & 1];
          s1 += v; q1 += v * v;
        }
#pragma unroll
        for (int m = 1; m < 16; m <<= 1) {
          s1 += __shfl_xor(s1, m); q1 += __shfl_xor(q1, m);
        }
        float s2 = __shfl_xor(s1, 16), q2 = __shfl_xor(q1, 16);
        float Sx = (cg & 16) ? s1 : s2;
        float Qx = (cg & 16) ? q1 : q2;
        float mu = Sx * (1.f / HID);
        float va = Qx * (1.f / HID) - mu * mu;
        float iv = 1.f / sqrtf(va + 1e-5f);
#pragma unroll
        for (int j = 0; j < 8; ++j) {
          float a = (acc1[r][j >> 1][j & 1] - mu) * iv * gg[j] + be[j];
          acc1[r][j >> 1][j & 1] = fmaxf(a, 0.f);
        }
      }
    }

    // ================= phase 3: h = a @ W2 + b2 (two 128-k halves) =========
    f2 acc2[RPG][2];
#pragma unroll
    for (int r = 0; r < RPG; ++r)
#pragma unroll
      for (int c = 0; c < 2; ++c) acc2[r][c] = (f2){0.f, 0.f};

#pragma unroll 1
    for (int half = 0; half < 2; ++half) {
      __syncthreads();
      if ((cg >> 4) == half) {
#pragma unroll
        for (int j = 0; j < 8; ++j) {
          int kl = (j >> 2) * 64 + u * 4 + (j & 3);
#pragma unroll
          for (int g = 0; g < RPG; ++g)
            as_[kl * HSP + rg * RPG + g] = acc1[g][j >> 1][j & 1];
        }
      }
      __syncthreads();
#pragma unroll 1
      for (int kc = 0; kc < 8; ++kc) {
#pragma unroll
        for (int v = 0; v < 2; ++v) {
          int idx = v * 256 + tid;
          int k = idx >> 5, c4 = idx & 31;
          *(float4*)&ws2[k * 132 + c4 * 4] =
              *(const float4*)&W2[(size_t)(half * 128 + kc * 16 + k) * CD + c4 * 4];
        }
        __syncthreads();
#pragma unroll 2
        for (int kk = 0; kk < 16; ++kk) {
          f2 arp[RPG / 2], w2p[2];
#pragma unroll
          for (int g = 0; g < RPG / 4; ++g)
            *(float4*)&arp[g * 2] =
                *(const float4*)&as_[(kc * 16 + kk) * HSP + rg * RPG + g * 4];
          *(float4*)&w2p[0] = *(const float4*)&ws2[kk * 132 + cg * 4];
#pragma unroll
          for (int r2 = 0; r2 < RPG / 2; ++r2) {
#pragma unroll
            for (int c = 0; c < 2; ++c) PKLO(acc2[2 * r2][c], arp[r2], w2p[c]);
#pragma unroll
            for (int c = 0; c < 2; ++c) PKHI(acc2[2 * r2 + 1][c], arp[r2], w2p[c]);
          }
        }
        __syncthreads();
      }
    }
    {
      float4 bv = *(const float4*)&b2[cg * 4];
      float bb2[4] = {bv.x, bv.y, bv.z, bv.w};
#pragma unroll
      for (int c = 0; c < 4; ++c) {
#pragma unroll
        for (int g = 0; g < RPG / 4; ++g)
          *(float4*)&hs[(cg * 4 + c) * HSP + rg * RPG + g * 4] =
              make_float4(acc2[g * 4 + 0][c >> 1][c & 1] + bb2[c],
                          acc2[g * 4 + 1][c >> 1][c & 1] + bb2[c],
                          acc2[g * 4 + 2][c >> 1][c & 1] + bb2[c],
                          acc2[g * 4 + 3][c >> 1][c & 1] + bb2[c]);
      }
    }
  } else {
    // root joint: h = z_j directly
#pragma unroll
    for (int v = 0; v < RB / 8; ++v) {
      int idx = v * 256 + tid;
      int r = idx >> 5, c4 = idx & 31;
      float4 vz = *(const float4*)&z[(size_t)(row0 + r) * rstride + (size_t)jj * CD + c4 * 4];
      hs[(c4 * 4 + 0) * HSP + r] = vz.x;
      hs[(c4 * 4 + 1) * HSP + r] = vz.y;
      hs[(c4 * 4 + 2) * HSP + r] = vz.z;
      hs[(c4 * 4 + 3) * HSP + r] = vz.w;
    }
  }

  // ====== phase 4: d = ||E||^2 - 2 h.E ; R4 rows x 8 codes per thread ======
  const int w4 = tid >> 6;     // wave owns rows w4*R4 .. +R4-1
  const int l4 = tid & 63;     // lane owns codes {l4*4..+3} and {256+l4*4..+3}
  float mnv[R4]; int mni[R4];
#pragma unroll
  for (int r = 0; r < R4; ++r) { mnv[r] = 3.402823e38f; mni[r] = 0; }
  const float* embJ = emb + (size_t)jj * NE * CD;
  const float* nrmJ = nrm + jj * NE;

#pragma unroll 1
  for (int p = 0; p < 2; ++p) {
    __syncthreads();  // hs ready (p=0); es/nsm WAR from previous chunk
    if (tid < 128) {
      *(float4*)&nsm[tid * 4] = *(const float4*)&nrmJ[p * 512 + tid * 4];
    }
    f2 acc4[R4][4];
#pragma unroll
    for (int r = 0; r < R4; ++r)
#pragma unroll
      for (int c = 0; c < 4; ++c) acc4[r][c] = (f2){0.f, 0.f};

#pragma unroll 1
    for (int kc = 0; kc < 8; ++kc) {
      // stage e chunk [16 dims][512 codes]
#pragma unroll
      for (int v = 0; v < 8; ++v) {
        int idx = v * 256 + tid;
        int n = idx >> 2, kq = idx & 3;
        float4 ev = *(const float4*)&embJ[(size_t)(p * 512 + n) * CD + kc * 16 + kq * 4];
        es[(kq * 4 + 0) * 516 + n] = ev.x;
        es[(kq * 4 + 1) * 516 + n] = ev.y;
        es[(kq * 4 + 2) * 516 + n] = ev.z;
        es[(kq * 4 + 3) * 516 + n] = ev.w;
      }
      __syncthreads();
#pragma unroll 2
      for (int kk = 0; kk < 16; ++kk) {
        int c = kc * 16 + kk;
        f2 hrp[R4 / 2], ecp[4];
#pragma unroll
        for (int g = 0; g < R4 / 4; ++g)
          *(float4*)&hrp[g * 2] = *(const float4*)&hs[c * HSP + w4 * R4 + g * 4];
        *(float4*)&ecp[0] = *(const float4*)&es[kk * 516 + l4 * 4];
        *(float4*)&ecp[2] = *(const float4*)&es[kk * 516 + 256 + l4 * 4];
#pragma unroll
        for (int r2 = 0; r2 < R4 / 2; ++r2) {
#pragma unroll
          for (int c2 = 0; c2 < 4; ++c2) PKLO(acc4[2 * r2][c2], hrp[r2], ecp[c2]);
#pragma unroll
          for (int c2 = 0; c2 < 4; ++c2) PKHI(acc4[2 * r2 + 1][c2], hrp[r2], ecp[c2]);
        }
      }
      __syncthreads();
    }
    // min update, ascending-n order with strict < (first-occurrence ties)
#pragma unroll
    for (int r = 0; r < R4; ++r) {
#pragma unroll
      for (int q = 0; q < 2; ++q) {
#pragma unroll
        for (int j = 0; j < 4; ++j) {
          int nl = q * 256 + l4 * 4 + j;
          int ci = q * 4 + j;
          float d = nsm[nl] - 2.f * acc4[r][ci >> 1][ci & 1];
          int n = p * 512 + nl;
          if (d < mnv[r]) { mnv[r] = d; mni[r] = n; }
        }
      }
    }
  }

  // cross-lane argmin reduce over 64 lanes, tie -> smaller index
#pragma unroll
  for (int r = 0; r < R4; ++r) {
    float mv = mnv[r]; int mi = mni[r];
#pragma unroll
    for (int m = 1; m < 64; m <<= 1) {
      float om = __shfl_xor(mv, m); int oi = __shfl_xor(mi, m);
      if (om < mv || (om == mv && oi < mi)) { mv = om; mi = oi; }
    }
    mnv[r] = mv; mni[r] = mi;
  }

  // gather e, write z_q + indices, accumulate loss (lane covers 2 cols)
  float lsum = 0.f;
#pragma unroll
  for (int r = 0; r < R4; ++r) {
    int row = w4 * R4 + r;
    int id = mni[r];
    const float* erow = embJ + (size_t)id * CD;
    float2 ev = *(const float2*)&erow[l4 * 2];
    float h0 = hs[(l4 * 2 + 0) * HSP + row];
    float h1 = hs[(l4 * 2 + 1) * HSP + row];
    float dx = ev.x - h0, dy = ev.y - h1;
    lsum += dx * dx + dy * dy;
    *(float2*)&zq[(size_t)(row0 + row) * rstride + (size_t)jj * CD + l4 * 2] = ev;
    if (l4 == r) idx_out[(size_t)(row0 + row) * NJ + jj] = (float)id;
  }
#pragma unroll
  for (int m = 1; m < 64; m <<= 1) lsum += __shfl_xor(lsum, m);
  if (l4 == 0) wsum[w4] = lsum;
  __syncthreads();
  if (tid == 0) partials[pbase + blockIdx.x] = wsum[0] + wsum[1] + wsum[2] + wsum[3];
}

// ---------------------------------------------------------------------------
// deterministic loss reduction
// ---------------------------------------------------------------------------
__global__ __launch_bounds__(256) void loss_reduce(const float* __restrict__ p, int n,
                                                   float* __restrict__ out) {
  __shared__ float ws[4];
  float s = 0.f;
  for (int i = threadIdx.x; i < n; i += 256) s += p[i];
#pragma unroll
  for (int m = 1; m < 64; m <<= 1) s += __shfl_xor(s, m);
  if ((threadIdx.x & 63) == 0) ws[threadIdx.x >> 6] = s;
  __syncthreads();
  if (threadIdx.x == 0)
    out[0] = (ws[0] + ws[1] + ws[2] + ws[3]) * (1.25f / (1048576.f * 32.f));
}

extern "C" void kernel_launch(void* const* d_in, const int* in_sizes, int n_in,
                              void* d_out, int out_size, void* d_ws, size_t ws_size,
                              hipStream_t stream) {
  const float* z = (const float*)d_in[0];
  const float* emb = (const float*)d_in[1];
  const float* W1 = (const float*)d_in[2];
  const float* b1 = (const float*)d_in[3];
  const float* lng = (const float*)d_in[4];
  const float* lnb = (const float*)d_in[5];
  const float* W2 = (const float*)d_in[6];
  const float* b2 = (const float*)d_in[7];

  float* zq = (float*)d_out;
  float* loss = zq + (size_t)ROWS * NJ * CD;  // 33,554,432
  float* idxo = loss + 1;

  float* nrm = (float*)d_ws;           // NJ*NE floats
  float* partials = nrm + NJ * NE;     // <= 5760 floats

  norms_kernel<<<NJ * NE * 4 / 256, 256, 0, stream>>>(emb, nrm);

  static const Lv levels[11] = {
      {1, {0, 0, 0, 0, 0}, {-1, 0, 0, 0, 0}},
      {3, {1, 6, 11, 0, 0}, {0, 0, 0, 0, 0}},
      {3, {2, 7, 12, 0, 0}, {1, 6, 11, 0, 0}},
      {5, {3, 8, 13, 16, 24}, {2, 7, 12, 12, 12}},
      {5, {4, 9, 14, 17, 25}, {3, 8, 13, 16, 24}},
      {5, {5, 10, 15, 18, 26}, {4, 9, 14, 17, 25}},
      {2, {19, 27, 0, 0, 0}, {18, 26, 0, 0, 0}},
      {2, {20, 28, 0, 0, 0}, {19, 27, 0, 0, 0}},
      {2, {21, 29, 0, 0, 0}, {20, 28, 0, 0, 0}},
      {2, {22, 30, 0, 0, 0}, {21, 29, 0, 0, 0}},
      {2, {23, 31, 0, 0, 0}, {22, 30, 0, 0, 0}},
  };
  // RB per level: root (phase-4-only) 16; nj<=2 levels 32; big levels 64
  static const int rbs[11] = {16, 64, 64, 64, 64, 64, 32, 32, 32, 32, 32};

  int pbase = 0;
  for (int L = 0; L < 11; ++L) {
    int bpj = ROWS / rbs[L];
    int blocks = levels[L].nj * bpj;
    if (rbs[L] == 64) {
      fused_level<64><<<blocks, 256, 0, stream>>>(
          z, emb, W1, b1, lng, lnb, W2, b2, nrm, zq, idxo, partials, levels[L], pbase);
    } else if (rbs[L] == 32) {
      fused_level<32><<<blocks, 256, 0, stream>>>(
          z, emb, W1, b1, lng, lnb, W2, b2, nrm, zq, idxo, partials, levels[L], pbase);
    } else {
      fused_level<16><<<blocks, 256, 0, stream>>>(
          z, emb, W1, b1, lng, lnb, W2, b2, nrm, zq, idxo, partials, levels[L], pbase);
    }
    pbase += blocks;
  }
  loss_reduce<<<1, 256, 0, stream>>>(partials, pbase, loss);
}